// Round 2
// baseline (496.714 us; speedup 1.0000x reference)
//
#include <hip/hip_runtime.h>

// Multi-step integrate-and-fire (T=16 scan), x_seq: (16,32,128,32,32) fp32.
// ~268 MB in + ~268 MB out per launch; memory-latency-bound so far.
//
// R1: NT stores for output (keep input hot in L3) -- kept.
// R3: preload-16 attempt FAILED: VGPR stayed 36 -> compiler sank the loads
//     back into the scan loop (loops re-fused), ~1 load in flight, and each
//     iteration's s_waitcnt also drains older NT stores (shared vmcnt).
//     173 -> 185us.
// R4: enforce the preload with __builtin_amdgcn_sched_barrier(0): no
//     instruction may cross, so regalloc must keep all 16 f32x4 live
//     (~64 payload VGPRs, 16 loads in flight per wave). Scan-phase waits
//     become incremental vmcnt(15..0); stores are younger than every load
//     being waited on, so store retire latency stops blocking loads.
//     Verify via VGPR_Count ~80-100 (36 => sinking happened again).
//     Predicted: dur ~100-130us, 3.2-4 TB/s.

#define T_STEPS 16

typedef float f32x4 __attribute__((ext_vector_type(4)));

__global__ __launch_bounds__(256) void if_scan_kernel(
    const f32x4* __restrict__ x, f32x4* __restrict__ out, int n4) {
    int i = blockIdx.x * blockDim.x + threadIdx.x;
    if (i >= n4) return;

    // Phase 1: issue all 16 independent slice loads back-to-back.
    f32x4 xv[T_STEPS];
#pragma unroll
    for (int t = 0; t < T_STEPS; ++t) {
        xv[t] = x[(size_t)t * (size_t)n4 + (size_t)i];
    }

    // Hard scheduling fence: nothing crosses. Forces all loads to be issued
    // (and their 64 result VGPRs allocated) before any scan work.
    __builtin_amdgcn_sched_barrier(0);

    // Phase 2: serial scan (pure VALU) + NT stores; drains vmcnt 15->0.
    f32x4 v = (f32x4)(0.f);
#pragma unroll
    for (int t = 0; t < T_STEPS; ++t) {
        v += xv[t];
        f32x4 s;
        s.x = (v.x >= 1.0f) ? 1.0f : 0.0f;
        s.y = (v.y >= 1.0f) ? 1.0f : 0.0f;
        s.z = (v.z >= 1.0f) ? 1.0f : 0.0f;
        s.w = (v.w >= 1.0f) ? 1.0f : 0.0f;
        v -= s;
        __builtin_nontemporal_store(s, &out[(size_t)t * (size_t)n4 + (size_t)i]);
    }
}

extern "C" void kernel_launch(void* const* d_in, const int* in_sizes, int n_in,
                              void* d_out, int out_size, void* d_ws, size_t ws_size,
                              hipStream_t stream) {
    const float* x = (const float*)d_in[0];
    float* out = (float*)d_out;

    int total = in_sizes[0];             // 16*32*128*32*32 = 67108864
    int per_step = total / T_STEPS;      // 4194304 floats per timestep
    int n4 = per_step / 4;               // 1048576 float4 per timestep

    dim3 block(256);
    dim3 grid((n4 + block.x - 1) / block.x);   // 4096 blocks
    if_scan_kernel<<<grid, block, 0, stream>>>(
        (const f32x4*)x, (f32x4*)out, n4);
}

// Round 3
// 491.505 us; speedup vs baseline: 1.0106x; 1.0106x over previous
//
#include <hip/hip_runtime.h>

// Multi-step integrate-and-fire (T=16 scan), x_seq: (16,32,128,32,32) fp32.
// ~268 MB in (half L3-served) + ~268 MB out; memory-latency-bound so far.
//
// R1: NT stores for output (keep input hot in L3) -- kept.
// R3: preload-16 via plain unrolled loops FAILED (VGPR 36: compiler re-fused
//     the loops at IR level, loads sunk back into the scan). 173 -> 185us.
// R4: sched_barrier(0) FAILED the same way (VGPR 36): sched.barrier only
//     constrains the machine scheduler; IR-level sinking ignores it. 220us.
// R5: root cause: fused loop = load -> waitcnt -> compute -> NT-store per t.
//     vmcnt is one FIFO over loads AND stores, so each load-wait drains the
//     previous iteration's NT stores -- whose ack comes from the HBM
//     controller (~900cy, L2 bypassed). 16 store-ack round trips per wave.
//     Fix: pin each loaded value with asm volatile("" : "+v"(xv[t])) --
//     opaque at IR level, so all 16 loads must issue before the scan.
//     Then every store is younger than every pending load in the FIFO and
//     load-waits never block on stores.
//     Verify: VGPR ~80-100 (36 => pin failed). Predict ~95-130us, 3.5+ TB/s.

#define T_STEPS 16

typedef float f32x4 __attribute__((ext_vector_type(4)));

__global__ __launch_bounds__(256) void if_scan_kernel(
    const f32x4* __restrict__ x, f32x4* __restrict__ out, int n4) {
    int i = blockIdx.x * blockDim.x + threadIdx.x;
    if (i >= n4) return;

    // Phase 1: issue all 16 independent slice loads back-to-back.
    f32x4 xv[T_STEPS];
#pragma unroll
    for (int t = 0; t < T_STEPS; ++t) {
        xv[t] = x[(size_t)t * (size_t)n4 + (size_t)i];
    }

    // Liveness pins: volatile asm reads+writes each value. IR passes cannot
    // sink the loads past these (data dependency into opaque asm), so all 16
    // loads are in flight before any scan work. Zero instructions emitted.
#pragma unroll
    for (int t = 0; t < T_STEPS; ++t) {
        asm volatile("" : "+v"(xv[t]));
    }

    // Phase 2: serial scan (pure VALU) + NT stores; waits drain vmcnt
    // incrementally (15..0) and never include a store.
    f32x4 v = (f32x4)(0.f);
#pragma unroll
    for (int t = 0; t < T_STEPS; ++t) {
        v += xv[t];
        f32x4 s;
        s.x = (v.x >= 1.0f) ? 1.0f : 0.0f;
        s.y = (v.y >= 1.0f) ? 1.0f : 0.0f;
        s.z = (v.z >= 1.0f) ? 1.0f : 0.0f;
        s.w = (v.w >= 1.0f) ? 1.0f : 0.0f;
        v -= s;
        __builtin_nontemporal_store(s, &out[(size_t)t * (size_t)n4 + (size_t)i]);
    }
}

extern "C" void kernel_launch(void* const* d_in, const int* in_sizes, int n_in,
                              void* d_out, int out_size, void* d_ws, size_t ws_size,
                              hipStream_t stream) {
    const float* x = (const float*)d_in[0];
    float* out = (float*)d_out;

    int total = in_sizes[0];             // 16*32*128*32*32 = 67108864
    int per_step = total / T_STEPS;      // 4194304 floats per timestep
    int n4 = per_step / 4;               // 1048576 float4 per timestep

    dim3 block(256);
    dim3 grid((n4 + block.x - 1) / block.x);   // 4096 blocks
    if_scan_kernel<<<grid, block, 0, stream>>>(
        (const f32x4*)x, (f32x4*)out, n4);
}

// Round 4
// 442.670 us; speedup vs baseline: 1.1221x; 1.1103x over previous
//
#include <hip/hip_runtime.h>

// Multi-step integrate-and-fire (T=16 scan), x_seq: (16,32,128,32,32) fp32.
// ~268 MB in (half L3-served) + ~268 MB out.
//
// R1: NT stores for output (keep input hot in L3) -- kept.
// R3/R4/R5: three attempts to preload all 16 t-slices (plain unroll,
//     sched_barrier(0), per-value asm pins) ALL collapsed back to the fused
//     loop (VGPR stuck at 36) and regressed (185/220/211us vs R0's 173).
//     Also: plain-store write BW (1.86 TB/s, prev session) ~= NT write BW
//     (1.68 TB/s) despite 4x different ack latency => the per-iteration
//     store-ack wait chain is NOT the limiter.
// R6: theory: MLP-bound. Measured BW matches in-flight-bytes arithmetic:
//     R0 ~32KB/CU in flight / ~400ns ~= 10 GB/s/CU ~= measured 2.5 TB/s.
//     Only positive signal ever: streams/thread (R0 2-wide beat R3 1-wide).
//     So raise PER-ITERATION independent loads -- inside one iteration the
//     scheduler keeps them together instead of collapsing them.
//     4 float4/thread, blockDim-strided so every load instruction is a fully
//     coalesced contiguous 1KB/wave (R0's i,i+1 pattern spanned 4KB per
//     instr using half the bytes).
//     Verify: VGPR ~64-80. Predict dur ~110-135us, 3.2-3.8 TB/s;
//     if unchanged ~173us => MLP falsified, next A/B is plain vs NT stores.

#define T_STEPS 16
#define K_ELEMS 4   // float4 per thread

typedef float f32x4 __attribute__((ext_vector_type(4)));

__global__ __launch_bounds__(256) void if_scan_kernel(
    const f32x4* __restrict__ x, f32x4* __restrict__ out, int n4) {
    // Block handles a contiguous chunk of K_ELEMS*256 float4 per t-slice;
    // thread's k-th element is blockDim-strided => coalesced per instruction.
    int base = blockIdx.x * (blockDim.x * K_ELEMS) + threadIdx.x;

    f32x4 v[K_ELEMS];
#pragma unroll
    for (int k = 0; k < K_ELEMS; ++k) v[k] = (f32x4)(0.f);

#pragma unroll
    for (int t = 0; t < T_STEPS; ++t) {
        size_t off = (size_t)t * (size_t)n4 + (size_t)base;

        // 4 independent coalesced loads issued back-to-back.
        f32x4 a[K_ELEMS];
#pragma unroll
        for (int k = 0; k < K_ELEMS; ++k) {
            a[k] = x[off + (size_t)(k * 256)];
        }

        f32x4 s[K_ELEMS];
#pragma unroll
        for (int k = 0; k < K_ELEMS; ++k) {
            v[k] += a[k];
            s[k].x = (v[k].x >= 1.0f) ? 1.0f : 0.0f;
            s[k].y = (v[k].y >= 1.0f) ? 1.0f : 0.0f;
            s[k].z = (v[k].z >= 1.0f) ? 1.0f : 0.0f;
            s[k].w = (v[k].w >= 1.0f) ? 1.0f : 0.0f;
            v[k] -= s[k];
        }

#pragma unroll
        for (int k = 0; k < K_ELEMS; ++k) {
            __builtin_nontemporal_store(s[k], &out[off + (size_t)(k * 256)]);
        }
    }
}

extern "C" void kernel_launch(void* const* d_in, const int* in_sizes, int n_in,
                              void* d_out, int out_size, void* d_ws, size_t ws_size,
                              hipStream_t stream) {
    const float* x = (const float*)d_in[0];
    float* out = (float*)d_out;

    int total = in_sizes[0];             // 16*32*128*32*32 = 67108864
    int per_step = total / T_STEPS;      // 4194304 floats per timestep
    int n4 = per_step / 4;               // 1048576 float4 per timestep

    dim3 block(256);
    // n4 / (256*4) = 1024 blocks; n4 is an exact multiple (2^20).
    dim3 grid(n4 / (block.x * K_ELEMS));
    if_scan_kernel<<<grid, block, 0, stream>>>(
        (const f32x4*)x, (f32x4*)out, n4);
}

// Round 5
// 429.460 us; speedup vs baseline: 1.1566x; 1.0308x over previous
//
#include <hip/hip_runtime.h>

// Multi-step integrate-and-fire (T=16 scan), x_seq: (16,32,128,32,32) fp32.
// ~268 MB in + ~268 MB out.
//
// R3/R4/R5: preload-16 attempts all collapsed (VGPR 36), regressed. Dead end.
// R6: 4 float4/thread, blockDim-strided (100% per-instruction coalescing):
//     kernel ~173 -> ~157us. Modest, far below the MLP prediction.
// R7: unifying observation: EVERY round used NT stores and EVERY round's
//     write stream ran at 1.4-1.7 TB/s (R0 292MB/173us=1.69, R6 262/157=1.67)
//     while the harness's fillBufferAligned does PLAIN stores at 6.5 TB/s
//     with 8 VGPRs and 10% occupancy, and m13's read+write copy hits 6.3.
//     Theory: NT stores bypass L2 and retire through a narrow MC path
//     (~1.7 TB/s cap); the kernel is NT-write-throughput-bound.
//     Previous session's "plain worse" was confounded: stores were then
//     32B-strided partial lines (RFO overhead). R6 writes full 64B lines,
//     so write-allocate adds no read traffic (fill: 1GiB written, 14KB read).
//     A/B: identical structure, plain stores.
//     Predict: FETCH 131->~200-270MB (output evicts input from L3),
//     WRITE ~262-300MB, kernel ~90-115us (~4.5-5.5 TB/s), composite ~380-400.
//     If unchanged => NT falsified; suspect the 16MB-strided t-walk next.

#define T_STEPS 16
#define K_ELEMS 4   // float4 per thread

typedef float f32x4 __attribute__((ext_vector_type(4)));

__global__ __launch_bounds__(256) void if_scan_kernel(
    const f32x4* __restrict__ x, f32x4* __restrict__ out, int n4) {
    // Block handles a contiguous chunk of K_ELEMS*256 float4 per t-slice;
    // thread's k-th element is blockDim-strided => coalesced per instruction.
    int base = blockIdx.x * (blockDim.x * K_ELEMS) + threadIdx.x;

    f32x4 v[K_ELEMS];
#pragma unroll
    for (int k = 0; k < K_ELEMS; ++k) v[k] = (f32x4)(0.f);

#pragma unroll
    for (int t = 0; t < T_STEPS; ++t) {
        size_t off = (size_t)t * (size_t)n4 + (size_t)base;

        // 4 independent coalesced loads issued back-to-back.
        f32x4 a[K_ELEMS];
#pragma unroll
        for (int k = 0; k < K_ELEMS; ++k) {
            a[k] = x[off + (size_t)(k * 256)];
        }

        f32x4 s[K_ELEMS];
#pragma unroll
        for (int k = 0; k < K_ELEMS; ++k) {
            v[k] += a[k];
            s[k].x = (v[k].x >= 1.0f) ? 1.0f : 0.0f;
            s[k].y = (v[k].y >= 1.0f) ? 1.0f : 0.0f;
            s[k].z = (v[k].z >= 1.0f) ? 1.0f : 0.0f;
            s[k].w = (v[k].w >= 1.0f) ? 1.0f : 0.0f;
            v[k] -= s[k];
        }

        // Plain stores: full 64B lines, L2-absorbed, no NT bypass path.
#pragma unroll
        for (int k = 0; k < K_ELEMS; ++k) {
            out[off + (size_t)(k * 256)] = s[k];
        }
    }
}

extern "C" void kernel_launch(void* const* d_in, const int* in_sizes, int n_in,
                              void* d_out, int out_size, void* d_ws, size_t ws_size,
                              hipStream_t stream) {
    const float* x = (const float*)d_in[0];
    float* out = (float*)d_out;

    int total = in_sizes[0];             // 16*32*128*32*32 = 67108864
    int per_step = total / T_STEPS;      // 4194304 floats per timestep
    int n4 = per_step / 4;               // 1048576 float4 per timestep

    dim3 block(256);
    // n4 / (256*4) = 1024 blocks; n4 is an exact multiple (2^20).
    dim3 grid(n4 / (block.x * K_ELEMS));
    if_scan_kernel<<<grid, block, 0, stream>>>(
        (const f32x4*)x, (f32x4*)out, n4);
}

// Round 6
// 428.675 us; speedup vs baseline: 1.1587x; 1.0018x over previous
//
#include <hip/hip_runtime.h>

// Multi-step integrate-and-fire (T=16 scan), x_seq: (16,32,128,32,32) fp32.
// ~268 MB in + ~268 MB out. Harness overhead (fill re-poison etc) ~286us of
// the composite dur_us; kernel-only times inferred from that.
//
// R3/R4/R5: 16-deep preload attempts all collapsed by the pressure-aware
//     scheduler (VGPR pinned at 36). Dead end at depth 16.
// R6: 4x float4/thread blockDim-strided coalescing: kernel ~173 -> ~157us.
// R7: plain stores instead of NT: ~157 -> ~143us (~3.6 TB/s). NT store path
//     confirmed harmful (1.7 TB/s write cap); plain full-line stores have no
//     RFO cost (fill kernel: 1 GiB written, 14.5 KB fetched, 6.5 TB/s).
// R8: still at ~58% of the 6.3 TB/s mixed-stream ceiling (m13 copy). VALU
//     3.5%, traffic near-ideal, stores fire-and-forget => remaining gap is
//     the per-iteration read-pipeline drain: loads(t+1) only issue after
//     wait+compute+store of t. Fix: depth-1 ping-pong prefetch -- issue
//     loads for t+1 before consuming t. Costs +16 VGPR (no pressure cliff,
//     scheduler should keep it, unlike the depth-16 attempts).
//     Verify: VGPR ~56-72. Predict kernel ~100-120us (composite ~385-405);
//     if unchanged => mixed-stream ceiling, try XCD swizzle / store policy.

#define T_STEPS 16
#define K_ELEMS 4   // float4 per thread

typedef float f32x4 __attribute__((ext_vector_type(4)));

__global__ __launch_bounds__(256) void if_scan_kernel(
    const f32x4* __restrict__ x, f32x4* __restrict__ out, int n4) {
    int base = blockIdx.x * (blockDim.x * K_ELEMS) + threadIdx.x;

    f32x4 v[K_ELEMS];
#pragma unroll
    for (int k = 0; k < K_ELEMS; ++k) v[k] = (f32x4)(0.f);

    // Prologue: load t=0.
    f32x4 cur[K_ELEMS];
#pragma unroll
    for (int k = 0; k < K_ELEMS; ++k) {
        cur[k] = x[(size_t)base + (size_t)(k * 256)];
    }

#pragma unroll
    for (int t = 0; t < T_STEPS; ++t) {
        size_t off = (size_t)t * (size_t)n4 + (size_t)base;

        // Prefetch t+1 BEFORE consuming t: wave's read stream never drains.
        f32x4 nxt[K_ELEMS];
        if (t + 1 < T_STEPS) {
            size_t noff = off + (size_t)n4;
#pragma unroll
            for (int k = 0; k < K_ELEMS; ++k) {
                nxt[k] = x[noff + (size_t)(k * 256)];
            }
        }

        // Consume t: scan chain + plain full-line stores.
#pragma unroll
        for (int k = 0; k < K_ELEMS; ++k) {
            v[k] += cur[k];
            f32x4 s;
            s.x = (v[k].x >= 1.0f) ? 1.0f : 0.0f;
            s.y = (v[k].y >= 1.0f) ? 1.0f : 0.0f;
            s.z = (v[k].z >= 1.0f) ? 1.0f : 0.0f;
            s.w = (v[k].w >= 1.0f) ? 1.0f : 0.0f;
            v[k] -= s;
            out[off + (size_t)(k * 256)] = s;
        }

        // Rotate ping-pong buffer (SSA renaming, no real moves after unroll).
        if (t + 1 < T_STEPS) {
#pragma unroll
            for (int k = 0; k < K_ELEMS; ++k) cur[k] = nxt[k];
        }
    }
}

extern "C" void kernel_launch(void* const* d_in, const int* in_sizes, int n_in,
                              void* d_out, int out_size, void* d_ws, size_t ws_size,
                              hipStream_t stream) {
    const float* x = (const float*)d_in[0];
    float* out = (float*)d_out;

    int total = in_sizes[0];             // 16*32*128*32*32 = 67108864
    int per_step = total / T_STEPS;      // 4194304 floats per timestep
    int n4 = per_step / 4;               // 1048576 float4 per timestep

    dim3 block(256);
    dim3 grid(n4 / (block.x * K_ELEMS));   // 1024 blocks, exact
    if_scan_kernel<<<grid, block, 0, stream>>>(
        (const f32x4*)x, (f32x4*)out, n4);
}